// Round 1
// 257.751 us; speedup vs baseline: 1.0165x; 1.0165x over previous
//
#include <hip/hip_runtime.h>
#include <cstdint>
#include <cstddef>

#define M_DIM 4096   // B*S
#define N_DIM 4096   // DOUT
#define K_DIM 4096   // DIN
#define BM 256
#define BN 256
#define BKB 128      // K-tile in BYTES (= 128 i8 elems); 128B LDS rows, 0-conflict swizzle
#define KTILES (K_DIM / BKB)

typedef __attribute__((ext_vector_type(4))) int i32x4;

// async global->LDS, 16B per lane. LDS dest is wave-uniform base + lane*16.
__device__ __forceinline__ void async_copy16(const void* g, void* l) {
  __builtin_amdgcn_global_load_lds(
      (const __attribute__((address_space(1))) void*)g,
      (__attribute__((address_space(3))) void*)l,
      16, 0, 0);
}

// ---------------------------------------------------------------------------
// Kernel 1: per-row int8 quantization of x. One block per row (4096 rows).
// Outputs: xi (int8 [M][K]), sx[m] = rowmax/127, rs[m] = sum_k xi (as float,
// exact: |sum| <= 4096*127 < 2^24).
// ---------------------------------------------------------------------------
__global__ __launch_bounds__(256) void convert_x_kernel(
    const float* __restrict__ x, signed char* __restrict__ xi,
    float* __restrict__ sx, float* __restrict__ rs) {
  __shared__ float red[8];
  const int t = threadIdx.x;
  const size_t row = blockIdx.x;
  const float* xr = x + row * (size_t)K_DIM;

  float4 v[4];
  float amax = 0.f;
#pragma unroll
  for (int i = 0; i < 4; ++i) {
    v[i] = *(const float4*)(xr + (i * 256 + t) * 4);
    amax = fmaxf(amax, fmaxf(fmaxf(fabsf(v[i].x), fabsf(v[i].y)),
                             fmaxf(fabsf(v[i].z), fabsf(v[i].w))));
  }
#pragma unroll
  for (int o = 32; o > 0; o >>= 1)
    amax = fmaxf(amax, __shfl_down(amax, o, 64));
  if ((t & 63) == 0) red[t >> 6] = amax;
  __syncthreads();
  amax = fmaxf(fmaxf(fmaxf(red[0], red[1]), fmaxf(red[2], red[3])), 1e-20f);
  const float inv = 127.f / amax;

  int ssum = 0;
  signed char* out = xi + row * (size_t)K_DIM;
#pragma unroll
  for (int i = 0; i < 4; ++i) {
    const int ia = __float2int_rn(v[i].x * inv);
    const int ib = __float2int_rn(v[i].y * inv);
    const int ic = __float2int_rn(v[i].z * inv);
    const int id = __float2int_rn(v[i].w * inv);
    ssum += ia + ib + ic + id;
    const int pk =
        (ia & 255) | ((ib & 255) << 8) | ((ic & 255) << 16) | (id << 24);
    *(int*)(out + (i * 256 + t) * 4) = pk;
  }
  float fs = (float)ssum;
#pragma unroll
  for (int o = 32; o > 0; o >>= 1) fs += __shfl_down(fs, o, 64);
  if ((t & 63) == 0) red[4 + (t >> 6)] = fs;
  __syncthreads();
  if (t == 0) {
    rs[row] = red[4] + red[5] + red[6] + red[7];
    sx[row] = amax * (1.f / 127.f);
  }
}

// ---------------------------------------------------------------------------
// Kernel 2: q int32 [K][N] -> qsT int8 [N][K], value (q-128). 64x64 tile.
// ---------------------------------------------------------------------------
__global__ __launch_bounds__(256) void convert_w_kernel(
    const int* __restrict__ q, signed char* __restrict__ qsT) {
  __shared__ __align__(16) int qtile[64][68];  // 68-int rows: 16B-aligned + pad
  const int t = threadIdx.x;
  const int k0 = (blockIdx.x & 63) << 6;
  const int n0 = (blockIdx.x >> 6) << 6;

  {
    const int c = t & 15;        // n-chunk (4 ints)
    const int r0 = t >> 4;       // k-row base
#pragma unroll
    for (int i = 0; i < 4; ++i) {
      const int r = r0 + i * 16;
      const int4 v = *(const int4*)(q + (size_t)(k0 + r) * N_DIM + n0 + c * 4);
      *(int4*)&qtile[r][c * 4] = v;
    }
  }
  __syncthreads();
  {
    const int kc = t & 15;   // k-chunk: rows kc*4 .. kc*4+3
    const int g = t >> 4;    // n-group: cols g*4 .. g*4+3
    int4 v[4];
#pragma unroll
    for (int i = 0; i < 4; ++i) v[i] = *(const int4*)&qtile[kc * 4 + i][g * 4];
#pragma unroll
    for (int j = 0; j < 4; ++j) {
      const int b0 = ((&v[0].x)[j] - 128) & 255;
      const int b1 = ((&v[1].x)[j] - 128) & 255;
      const int b2 = ((&v[2].x)[j] - 128) & 255;
      const int b3 = ((&v[3].x)[j] - 128) & 255;
      const int pk = b0 | (b1 << 8) | (b2 << 16) | (b3 << 24);
      *(int*)(qsT + (size_t)(n0 + g * 4 + j) * K_DIM + k0 + kc * 4) = pk;
    }
  }
}

// ---------------------------------------------------------------------------
// Kernel 3: 256x256-tile phased i8 GEMM (8-phase-template port, R-this-round).
//   - 8 waves (2M x 4N), per-wave output 128x64, acc[8][4] i32x4.
//   - 2-deep LDS double buffer (128 KiB total): stage tile t+1 (8x
//     global_load_lds dwordx4) issued at the TOP of tile t's compute, single
//     counted-down wait (lgkmcnt0 + vmcnt0) + raw s_barrier at tile end.
//     No __syncthreads => no compiler-inserted full drains inside phases.
//   - 4 phases/K-tile of {ds_read subtile, s_barrier, setprio(1), 16 MFMA,
//     setprio(0), s_barrier}  (T3 structure; T5 setprio).
//   - LDS geometry identical to verified R3 kernel: 128B rows, 8x16B chunks,
//     stored chunk = logical ^ (row&7); measured 0 bank conflicts.
//   - T1: XCD-aware bijective block swizzle (256 wgs, 256%8==0).
// mfma_i32_16x16x64_i8: lane holds A[row=lane&15][k=(lane>>4)*16+j] (16
// contiguous k-bytes = one 16B chunk); 2 K-steps (kh) per 128B row.
// C/D: col=lane&15, row=quad*4+r.
// ---------------------------------------------------------------------------
__global__ __launch_bounds__(512, 2) void gemm_kernel(
    const signed char* __restrict__ A,   // [M][K] i8
    const signed char* __restrict__ Bt,  // [N][K] i8
    const float* __restrict__ bias, const float* __restrict__ sx,
    const float* __restrict__ rs, const float* __restrict__ scale_p,
    const float* __restrict__ zp_p, float* __restrict__ C) {
  __shared__ __align__(16) signed char As[2][BM * BKB];  // 2 x 32 KB
  __shared__ __align__(16) signed char Bs[2][BN * BKB];  // 2 x 32 KB

  const int tid = threadIdx.x;
  const int wave = tid >> 6;   // 0..7
  const int lane = tid & 63;
  const int wm = wave >> 2;    // 0..1  (M half)
  const int wn = wave & 3;     // 0..3  (N quarter)

  // T1: XCD-aware bijective swizzle; grid=256, 32 consecutive per XCD.
  const int swz = (blockIdx.x & 7) * 32 + (blockIdx.x >> 3);
  const int bm = swz & 15;   // M fastest within an XCD chunk -> B panel reuse
  const int bn = swz >> 4;
  const size_t m0 = (size_t)bm * BM;
  const size_t n0 = (size_t)bn * BN;

  // staging lane decomposition (identical to verified kernel)
  const int srow = lane >> 3;                   // 0..7 row within 1KB issue
  const int schunk = (lane & 7) ^ srow;         // swizzled global 16B chunk

  // fragment lane decomposition
  const int quad = lane >> 4;
  const int lrow = lane & 15;
  const int rsw = lrow & 7;

  const signed char* Abase = A + m0 * K_DIM + schunk * 16;
  const signed char* Bbase = Bt + n0 * K_DIM + schunk * 16;

  i32x4 acc[8][4];
  const i32x4 zero = {0, 0, 0, 0};
#pragma unroll
  for (int i = 0; i < 8; ++i)
#pragma unroll
    for (int j = 0; j < 4; ++j) acc[i][j] = zero;

  // stage one K-tile (A 32KB + B 32KB) into buffer b: 8 issues/wave.
  auto stage = [&](int b, int k0) {
#pragma unroll
    for (int j = 0; j < 4; ++j) {
      const int rbase = j * 64 + wave * 8;  // wave-uniform
      const size_t go = (size_t)(rbase + srow) * K_DIM + k0;
      async_copy16(Abase + go, (void*)&As[b][rbase * BKB]);
      async_copy16(Bbase + go, (void*)&Bs[b][rbase * BKB]);
    }
  };

#define LDA(ig)                                                              \
  do {                                                                       \
    _Pragma("unroll") for (int kh = 0; kh < 2; ++kh)                         \
        _Pragma("unroll") for (int t = 0; t < 4; ++t) {                      \
      const int ar = wm * 128 + (ig) * 64 + t * 16 + lrow;                   \
      av[kh][t] =                                                            \
          *(const i32x4*)(as + ar * BKB + ((((kh << 2) | quad) ^ rsw) << 4));\
    }                                                                        \
  } while (0)

#define LDB(jg)                                                              \
  do {                                                                       \
    _Pragma("unroll") for (int kh = 0; kh < 2; ++kh)                         \
        _Pragma("unroll") for (int t = 0; t < 2; ++t) {                      \
      const int br = wn * 64 + ((jg) * 2 + t) * 16 + lrow;                   \
      bv[kh][(jg) * 2 + t] =                                                 \
          *(const i32x4*)(bs + br * BKB + ((((kh << 2) | quad) ^ rsw) << 4));\
    }                                                                        \
  } while (0)

#define MFMA16(ibase, j0)                                                    \
  do {                                                                       \
    __builtin_amdgcn_s_setprio(1);                                           \
    _Pragma("unroll") for (int kh = 0; kh < 2; ++kh)                         \
        _Pragma("unroll") for (int t = 0; t < 4; ++t)                        \
            _Pragma("unroll") for (int j = 0; j < 2; ++j)                    \
        acc[(ibase) + t][(j0) + j] = __builtin_amdgcn_mfma_i32_16x16x64_i8(  \
            av[kh][t], bv[kh][(j0) + j], acc[(ibase) + t][(j0) + j], 0, 0,   \
            0);                                                              \
    __builtin_amdgcn_s_setprio(0);                                           \
  } while (0)

  // prologue: stage tile 0, drain, barrier.
  stage(0, 0);
  asm volatile("s_waitcnt vmcnt(0)" ::: "memory");
  __builtin_amdgcn_s_barrier();

#pragma unroll 2
  for (int kt = 0; kt < KTILES; ++kt) {
    const int buf = kt & 1;
    const signed char* as = As[buf];
    const signed char* bs = Bs[buf];

    // Prefetch next tile into the other buffer. Its previous reader (tile
    // kt-1) finished before the barrier that started this tile -> no WAR.
    if (kt + 1 < KTILES) stage(buf ^ 1, (kt + 1) * BKB);

    i32x4 av[2][4], bv[2][4];

    // phase 0: A rows [wm*128, +63], B rows [wn*64, +31]
    LDA(0);
    LDB(0);
    __builtin_amdgcn_s_barrier();
    MFMA16(0, 0);
    __builtin_amdgcn_s_barrier();

    // phase 1: B rows [wn*64+32, +31]; reuse av
    LDB(1);
    __builtin_amdgcn_s_barrier();
    MFMA16(0, 2);
    __builtin_amdgcn_s_barrier();

    // phase 2: A rows [wm*128+64, +63]; reuse bv[2..3]
    LDA(1);
    __builtin_amdgcn_s_barrier();
    MFMA16(4, 2);
    __builtin_amdgcn_s_barrier();

    // phase 3: no new reads; reuse av (ig=1) and bv[0..1]
    MFMA16(4, 0);

    // tile end: all ds_reads serviced (lgkm) and next tile staged (vm),
    // then raw barrier. sched_barrier fences per rule #18 (both directions).
    __builtin_amdgcn_sched_barrier(0);
    asm volatile("s_waitcnt lgkmcnt(0)" ::: "memory");
    asm volatile("s_waitcnt vmcnt(0)" ::: "memory");
    __builtin_amdgcn_sched_barrier(0);
    __builtin_amdgcn_s_barrier();
  }

#undef LDA
#undef LDB
#undef MFMA16

  // Epilogue: y = a_m*accf + b_m + bias[n], a_m = scale*sx[m],
  // b_m = scale*sx[m]*(128-zp)*rs[m].
  const float scale = scale_p[0];
  const float c1 = 128.f - zp_p[0];
#pragma unroll
  for (int i = 0; i < 8; ++i) {
    const size_t mbase = m0 + wm * 128 + i * 16 + quad * 4;
    float am[4], bmv[4];
#pragma unroll
    for (int r = 0; r < 4; ++r) {
      const float a = scale * sx[mbase + r];
      am[r] = a;
      bmv[r] = a * c1 * rs[mbase + r];
    }
#pragma unroll
    for (int j = 0; j < 4; ++j) {
      const size_t n = n0 + wn * 64 + j * 16 + lrow;
      const float bv = bias[n];
#pragma unroll
      for (int r = 0; r < 4; ++r) {
        C[(mbase + r) * N_DIM + n] =
            fmaf(am[r], (float)acc[i][j][r], bmv[r] + bv);
      }
    }
  }
}

// ---------------------------------------------------------------------------
extern "C" void kernel_launch(void* const* d_in, const int* in_sizes, int n_in,
                              void* d_out, int out_size, void* d_ws,
                              size_t ws_size, hipStream_t stream) {
  const float* x = (const float*)d_in[0];
  const int* q = (const int*)d_in[1];
  const float* scale = (const float*)d_in[2];
  const float* zp = (const float*)d_in[3];
  const float* bias = (const float*)d_in[4];
  float* out = (float*)d_out;

  char* ws = (char*)d_ws;
  signed char* xi = (signed char*)ws;                           // 16 MB
  signed char* qsT = (signed char*)(ws + ((size_t)16 << 20));   // 16 MB
  float* sx = (float*)(ws + ((size_t)32 << 20));                // 16 KB
  float* rs = (float*)(ws + ((size_t)32 << 20) + (16 << 10));   // 16 KB

  convert_x_kernel<<<4096, 256, 0, stream>>>(x, xi, sx, rs);
  convert_w_kernel<<<4096, 256, 0, stream>>>(q, qsT);
  gemm_kernel<<<256, 512, 0, stream>>>(xi, qsT, bias, sx, rs, scale, zp, out);
}

// Round 2
// 252.370 us; speedup vs baseline: 1.0382x; 1.0213x over previous
//
#include <hip/hip_runtime.h>
#include <cstdint>
#include <cstddef>

#define M_DIM 4096   // B*S
#define N_DIM 4096   // DOUT
#define K_DIM 4096   // DIN
#define BM 256
#define BN 256
#define BKB 128      // K-tile in BYTES (= 128 i8 elems); 128B LDS rows
#define KTILES (K_DIM / BKB)

typedef __attribute__((ext_vector_type(4))) int i32x4;

// async global->LDS, 16B per lane. LDS dest is wave-uniform base + lane*16.
__device__ __forceinline__ void async_copy16(const void* g, void* l) {
  __builtin_amdgcn_global_load_lds(
      (const __attribute__((address_space(1))) void*)g,
      (__attribute__((address_space(3))) void*)l,
      16, 0, 0);
}

__device__ __forceinline__ void wait_vm6() {
  asm volatile("s_waitcnt vmcnt(6)" ::: "memory");
}
__device__ __forceinline__ void wait_vm4() {
  asm volatile("s_waitcnt vmcnt(4)" ::: "memory");
}
__device__ __forceinline__ void wait_vm2() {
  asm volatile("s_waitcnt vmcnt(2)" ::: "memory");
}
__device__ __forceinline__ void wait_vm0() {
  asm volatile("s_waitcnt vmcnt(0)" ::: "memory");
}
__device__ __forceinline__ void wait_none() {}

// ---------------------------------------------------------------------------
// Kernel 1: per-row int8 quantization of x. One block per row (4096 rows).
// ---------------------------------------------------------------------------
__global__ __launch_bounds__(256) void convert_x_kernel(
    const float* __restrict__ x, signed char* __restrict__ xi,
    float* __restrict__ sx, float* __restrict__ rs) {
  __shared__ float red[8];
  const int t = threadIdx.x;
  const size_t row = blockIdx.x;
  const float* xr = x + row * (size_t)K_DIM;

  float4 v[4];
  float amax = 0.f;
#pragma unroll
  for (int i = 0; i < 4; ++i) {
    v[i] = *(const float4*)(xr + (i * 256 + t) * 4);
    amax = fmaxf(amax, fmaxf(fmaxf(fabsf(v[i].x), fabsf(v[i].y)),
                             fmaxf(fabsf(v[i].z), fabsf(v[i].w))));
  }
#pragma unroll
  for (int o = 32; o > 0; o >>= 1)
    amax = fmaxf(amax, __shfl_down(amax, o, 64));
  if ((t & 63) == 0) red[t >> 6] = amax;
  __syncthreads();
  amax = fmaxf(fmaxf(fmaxf(red[0], red[1]), fmaxf(red[2], red[3])), 1e-20f);
  const float inv = 127.f / amax;

  int ssum = 0;
  signed char* out = xi + row * (size_t)K_DIM;
#pragma unroll
  for (int i = 0; i < 4; ++i) {
    const int ia = __float2int_rn(v[i].x * inv);
    const int ib = __float2int_rn(v[i].y * inv);
    const int ic = __float2int_rn(v[i].z * inv);
    const int id = __float2int_rn(v[i].w * inv);
    ssum += ia + ib + ic + id;
    const int pk =
        (ia & 255) | ((ib & 255) << 8) | ((ic & 255) << 16) | (id << 24);
    *(int*)(out + (i * 256 + t) * 4) = pk;
  }
  float fs = (float)ssum;
#pragma unroll
  for (int o = 32; o > 0; o >>= 1) fs += __shfl_down(fs, o, 64);
  if ((t & 63) == 0) red[4 + (t >> 6)] = fs;
  __syncthreads();
  if (t == 0) {
    rs[row] = red[4] + red[5] + red[6] + red[7];
    sx[row] = amax * (1.f / 127.f);
  }
}

// ---------------------------------------------------------------------------
// Kernel 2: q int32 [K][N] -> qsT int8 [N][K], value (q-128). 64x64 tile.
// ---------------------------------------------------------------------------
__global__ __launch_bounds__(256) void convert_w_kernel(
    const int* __restrict__ q, signed char* __restrict__ qsT) {
  __shared__ __align__(16) int qtile[64][68];  // 68-int rows: 16B-aligned + pad
  const int t = threadIdx.x;
  const int k0 = (blockIdx.x & 63) << 6;
  const int n0 = (blockIdx.x >> 6) << 6;

  {
    const int c = t & 15;        // n-chunk (4 ints)
    const int r0 = t >> 4;       // k-row base
#pragma unroll
    for (int i = 0; i < 4; ++i) {
      const int r = r0 + i * 16;
      const int4 v = *(const int4*)(q + (size_t)(k0 + r) * N_DIM + n0 + c * 4);
      *(int4*)&qtile[r][c * 4] = v;
    }
  }
  __syncthreads();
  {
    const int kc = t & 15;   // k-chunk: rows kc*4 .. kc*4+3
    const int g = t >> 4;    // n-group: cols g*4 .. g*4+3
    int4 v[4];
#pragma unroll
    for (int i = 0; i < 4; ++i) v[i] = *(const int4*)&qtile[kc * 4 + i][g * 4];
#pragma unroll
    for (int j = 0; j < 4; ++j) {
      const int b0 = ((&v[0].x)[j] - 128) & 255;
      const int b1 = ((&v[1].x)[j] - 128) & 255;
      const int b2 = ((&v[2].x)[j] - 128) & 255;
      const int b3 = ((&v[3].x)[j] - 128) & 255;
      const int pk = b0 | (b1 << 8) | (b2 << 16) | (b3 << 24);
      *(int*)(qsT + (size_t)(n0 + g * 4 + j) * K_DIM + k0 + kc * 4) = pk;
    }
  }
}

// ---------------------------------------------------------------------------
// Kernel 3: 256x256 i8 GEMM, m201-style counted-vmcnt schedule (T3+T4+T5).
//
// Half-tile staging (16 KB = 2 global_load_lds/lane), fixed order per tile:
//   S[4t+0] = A_lo(t)  rows {0-63, 128-191}     read at phase 0 (LDA(0))
//   S[4t+1] = B_0 (t)  rows {q*64+0 .. +31}     read at phase 0 (LDB(0))
//   S[4t+2] = B_1 (t)  rows {q*64+32 .. +63}    read at phase 1 (LDB(1))
//   S[4t+3] = A_hi(t)  rows {64-127, 192-255}   read at phase 2 (LDA(1))
// Stage pointer runs 7 half-tiles ahead of consumption; per-phase wait
// vmcnt(6) keeps 3 half-tiles in flight and NEVER drains to 0 in the main
// loop (m218: drain-0 ≈ single-buffer). Fits 2x64KB LDS because regions die
// phase-by-phase: A_lo/B_0 dead after p0, B_1 after p1, A_hi after p2, so
// tile t+2's halves land in buffer t&1 while tile t computes:
//   p0 stages A_hi(t+1)->buf^1; p1: A_lo(t+2)->buf; p2: B_0(t+2)->buf;
//   p3: B_1(t+2)->buf.  Wait at (t,p) covers landed-through S[4t+p+4];
// deadline table: (t,p0) needs S[4t+1] (covered by (t-1,p2): S[4t+2]),
// (t,p1) needs S[4t+2] (by (t,p0): S[4t+4]), (t,p2) needs S[4t+3] (by
// (t,p1): S[4t+5]).  Tail (tiles 30,31) drains 6->4->2->0.
// Every phase's ds_reads are consumed by that phase's MFMA -> lgkm drained
// before the post-MFMA barrier -> WAR-safe vs later-phase stages.
// ---------------------------------------------------------------------------
__global__ __launch_bounds__(512, 2) void gemm_kernel(
    const signed char* __restrict__ A,   // [M][K] i8
    const signed char* __restrict__ Bt,  // [N][K] i8
    const float* __restrict__ bias, const float* __restrict__ sx,
    const float* __restrict__ rs, const float* __restrict__ scale_p,
    const float* __restrict__ zp_p, float* __restrict__ C) {
  __shared__ __align__(16) signed char As[2][BM * BKB];  // 2 x 32 KB
  __shared__ __align__(16) signed char Bs[2][BN * BKB];  // 2 x 32 KB

  const int tid = threadIdx.x;
  const int wave = tid >> 6;   // 0..7
  const int lane = tid & 63;
  const int wm = wave >> 2;    // 0..1  (M half)
  const int wn = wave & 3;     // 0..3  (N quarter)

  // T1: XCD-aware bijective swizzle; grid=256, 32 consecutive per XCD.
  const int swz = (blockIdx.x & 7) * 32 + (blockIdx.x >> 3);
  const int bm = swz & 15;
  const int bn = swz >> 4;
  const size_t m0 = (size_t)bm * BM;
  const size_t n0 = (size_t)bn * BN;

  // staging lane decomposition: LDS dest linear, global src pre-swizzled.
  const int srow = lane >> 3;                   // 0..7 row within 1KB issue
  const int schunk = (lane & 7) ^ srow;         // swizzled global 16B chunk

  // fragment lane decomposition
  const int quad = lane >> 4;
  const int lrow = lane & 15;
  const int rsw = lrow & 7;

  const signed char* Abase = A + m0 * K_DIM + schunk * 16;
  const signed char* Bbase = Bt + n0 * K_DIM + schunk * 16;

  i32x4 acc[8][4];
  const i32x4 zero = {0, 0, 0, 0};
#pragma unroll
  for (int i = 0; i < 8; ++i)
#pragma unroll
    for (int j = 0; j < 4; ++j) acc[i][j] = zero;

  // Half-tile stagers: each = 2 global_load_lds per lane (16 KB total).
  // A half ig: rows r with ((r>>6)&1)==ig  (matches LDA(ig)'s union over wm)
  auto stageA = [&](int b, int k0, int ig) {
#pragma unroll
    for (int i = 0; i < 2; ++i) {
      const int rbase = i * 128 + ig * 64 + wave * 8;  // wave-uniform
      const size_t go = (size_t)(rbase + srow) * K_DIM + k0;
      async_copy16(Abase + go, (void*)&As[b][rbase * BKB]);
    }
  };
  // B half jg: rows r with ((r>>5)&1)==jg  (matches LDB(jg)'s union over wn)
  auto stageB = [&](int b, int k0, int jg) {
#pragma unroll
    for (int i = 0; i < 2; ++i) {
      const int rbase = (i * 2 + (wave >> 2)) * 64 + jg * 32 + (wave & 3) * 8;
      const size_t go = (size_t)(rbase + srow) * K_DIM + k0;
      async_copy16(Bbase + go, (void*)&Bs[b][rbase * BKB]);
    }
  };

#define LDA(ig)                                                              \
  do {                                                                       \
    _Pragma("unroll") for (int kh = 0; kh < 2; ++kh)                         \
        _Pragma("unroll") for (int t = 0; t < 4; ++t) {                      \
      const int ar = wm * 128 + (ig) * 64 + t * 16 + lrow;                   \
      av[kh][t] =                                                            \
          *(const i32x4*)(as + ar * BKB + ((((kh << 2) | quad) ^ rsw) << 4));\
    }                                                                        \
  } while (0)

#define LDB(jg)                                                              \
  do {                                                                       \
    _Pragma("unroll") for (int kh = 0; kh < 2; ++kh)                         \
        _Pragma("unroll") for (int t = 0; t < 2; ++t) {                      \
      const int br = wn * 64 + ((jg) * 2 + t) * 16 + lrow;                   \
      bv[kh][(jg) * 2 + t] =                                                 \
          *(const i32x4*)(bs + br * BKB + ((((kh << 2) | quad) ^ rsw) << 4));\
    }                                                                        \
  } while (0)

#define MFMA16(ibase, j0)                                                    \
  do {                                                                       \
    __builtin_amdgcn_s_setprio(1);                                           \
    _Pragma("unroll") for (int kh = 0; kh < 2; ++kh)                         \
        _Pragma("unroll") for (int t = 0; t < 4; ++t)                        \
            _Pragma("unroll") for (int j = 0; j < 2; ++j)                    \
        acc[(ibase) + t][(j0) + j] = __builtin_amdgcn_mfma_i32_16x16x64_i8(  \
            av[kh][t], bv[kh][(j0) + j], acc[(ibase) + t][(j0) + j], 0, 0,   \
            0);                                                              \
    __builtin_amdgcn_s_setprio(0);                                           \
  } while (0)

  // One tile: 4 phases. Per phase: ds_read frags, stage next half-tile,
  // counted vmcnt, barrier, MFMA, barrier. Phase 3: no reads/barriers (its
  // MFMA overlaps next tile's phase-0 ds_reads across waves).
#define DO_TILE(AS, BS, S0, W0, S1, W1, S2, W2, S3)                          \
  do {                                                                       \
    const signed char* as = (AS);                                            \
    const signed char* bs = (BS);                                            \
    i32x4 av[2][4], bv[2][4];                                                \
    LDA(0);                                                                  \
    LDB(0);                                                                  \
    S0;                                                                      \
    W0();                                                                    \
    __builtin_amdgcn_s_barrier();                                            \
    MFMA16(0, 0);                                                            \
    __builtin_amdgcn_s_barrier();                                            \
    LDB(1);                                                                  \
    S1;                                                                      \
    W1();                                                                    \
    __builtin_amdgcn_s_barrier();                                            \
    MFMA16(0, 2);                                                            \
    __builtin_amdgcn_s_barrier();                                            \
    LDA(1);                                                                  \
    S2;                                                                      \
    W2();                                                                    \
    __builtin_amdgcn_s_barrier();                                            \
    MFMA16(4, 2);                                                            \
    __builtin_amdgcn_s_barrier();                                            \
    S3;                                                                      \
    MFMA16(4, 0);                                                            \
  } while (0)

  // Prologue: stage S[0..6] = tile0 {A_lo,B_0,B_1,A_hi} + tile1 {A_lo,B_0,
  // B_1} (14 loads), wait vmcnt(6) -> tile0 fully landed, barrier.
  stageA(0, 0, 0);
  stageB(0, 0, 0);
  stageB(0, 0, 1);
  stageA(0, 0, 1);
  stageA(1, BKB, 0);
  stageB(1, BKB, 0);
  stageB(1, BKB, 1);
  wait_vm6();
  __builtin_amdgcn_s_barrier();

  // Main loop: tiles 0..29. Stages reference tiles t+1 (p0) and t+2 (p1-3),
  // max tile 31 at t=29.
#pragma unroll 2
  for (int kt = 0; kt < KTILES - 2; ++kt) {
    const int buf = kt & 1;
    const int k1 = (kt + 1) * BKB;
    const int k2 = (kt + 2) * BKB;
    DO_TILE(As[buf], Bs[buf],
            (stageA(buf ^ 1, k1, 1)), wait_vm6,   // S[4t+7]  = A_hi(t+1)
            (stageA(buf, k2, 0)),     wait_vm6,   // S[4t+8]  = A_lo(t+2)
            (stageB(buf, k2, 0)),     wait_vm6,   // S[4t+9]  = B_0 (t+2)
            (stageB(buf, k2, 1)));                // S[4t+10] = B_1 (t+2)
  }

  // Tail: tile 30 (stage last half S[127]=A_hi(31); drain 6->4->2),
  // tile 31 (drain 0 at p0; nothing outstanding after).
  DO_TILE(As[0], Bs[0], (stageA(1, 31 * BKB, 1)), wait_vm6, (void)0, wait_vm4,
          (void)0, wait_vm2, (void)0);
  DO_TILE(As[1], Bs[1], (void)0, wait_vm0, (void)0, wait_none, (void)0,
          wait_none, (void)0);

#undef LDA
#undef LDB
#undef MFMA16
#undef DO_TILE

  // Epilogue: y = a_m*accf + b_m + bias[n], a_m = scale*sx[m],
  // b_m = scale*sx[m]*(128-zp)*rs[m].
  const float scale = scale_p[0];
  const float c1 = 128.f - zp_p[0];
#pragma unroll
  for (int i = 0; i < 8; ++i) {
    const size_t mbase = m0 + wm * 128 + i * 16 + quad * 4;
    float am[4], bmv[4];
#pragma unroll
    for (int r = 0; r < 4; ++r) {
      const float a = scale * sx[mbase + r];
      am[r] = a;
      bmv[r] = a * c1 * rs[mbase + r];
    }
#pragma unroll
    for (int j = 0; j < 4; ++j) {
      const size_t n = n0 + wn * 64 + j * 16 + lrow;
      const float bv = bias[n];
#pragma unroll
      for (int r = 0; r < 4; ++r) {
        C[(mbase + r) * N_DIM + n] =
            fmaf(am[r], (float)acc[i][j][r], bmv[r] + bv);
      }
    }
  }
}

// ---------------------------------------------------------------------------
extern "C" void kernel_launch(void* const* d_in, const int* in_sizes, int n_in,
                              void* d_out, int out_size, void* d_ws,
                              size_t ws_size, hipStream_t stream) {
  const float* x = (const float*)d_in[0];
  const int* q = (const int*)d_in[1];
  const float* scale = (const float*)d_in[2];
  const float* zp = (const float*)d_in[3];
  const float* bias = (const float*)d_in[4];
  float* out = (float*)d_out;

  char* ws = (char*)d_ws;
  signed char* xi = (signed char*)ws;                           // 16 MB
  signed char* qsT = (signed char*)(ws + ((size_t)16 << 20));   // 16 MB
  float* sx = (float*)(ws + ((size_t)32 << 20));                // 16 KB
  float* rs = (float*)(ws + ((size_t)32 << 20) + (16 << 10));   // 16 KB

  convert_x_kernel<<<4096, 256, 0, stream>>>(x, xi, sx, rs);
  convert_w_kernel<<<4096, 256, 0, stream>>>(q, qsT);
  gemm_kernel<<<256, 512, 0, stream>>>(xi, qsT, bias, sx, rs, scale, zp, out);
}